// Round 1
// 391.214 us; speedup vs baseline: 1.0880x; 1.0880x over previous
//
#include <hip/hip_runtime.h>
#include <stdint.h>

// Problem constants
#define BDIM   512
#define NNODE  32
#define DDIM   300
#define NREL   5
#define NEDGE  256
#define VGLOB  50000
#define VSENSE 20000

#define K1PAD  1856   // stage-1 K: 6*300=1800 padded to 29*64
#define K2PAD  320    // stage-2 K: 300 padded to 5*64
#define TG_GLOB  391  // ceil(50000/128)
#define TG_SENSE 157  // ceil(20000/128)
#define TGTOT  548
#define GROWS  50048  // 391*128 padded rows
#define SROWS  20096  // 157*128
#define WROWS  70144  // GROWS+SROWS
#define NCHUNK 3      // stage-1 split-K chunks
#define KCH    10     // 64-wide k-steps per chunk (10+10+9 = 29)
#define NSCH   16     // scan chunks
#define SCHL   32     // scan chunk length

typedef __attribute__((ext_vector_type(8))) short short8;
typedef __attribute__((ext_vector_type(4))) float f32x4;

__device__ __forceinline__ unsigned short f2bf(float x) {
    unsigned int u = __float_as_uint(x);
    u += 0x7fffu + ((u >> 16) & 1u);   // RNE
    return (unsigned short)(u >> 16);
}

__device__ __forceinline__ float powi(float x, int n) {
    float r = 1.f, p = x;
    while (n) { if (n & 1) r *= p; p *= p; n >>= 1; }
    return r;
}

#define AS1 __attribute__((address_space(1)))
#define AS3 __attribute__((address_space(3)))
__device__ __forceinline__ void gload16(const void* gp, void* lp) {
    __builtin_amdgcn_global_load_lds((AS1 void*)gp, (AS3 void*)lp, 16, 0, 0);
}

// ---------------------------------------------------------------------------
// K1: per-batch graph prep. Build Z[b, k] (bf16, K1PAD cols). Fixed-order
// edge accumulation (deterministic across graph replays).
__global__ __launch_bounds__(256) void k_prep_z(
    const float* __restrict__ x, const int* __restrict__ ei,
    const int* __restrict__ et, unsigned short* __restrict__ Zb)
{
    int b = blockIdx.x, t = threadIdx.x;
    __shared__ int   cnt[NNODE * NREL];
    __shared__ float dinv[NNODE * NREL];
    __shared__ int   ssrc[NEDGE];
    __shared__ int   sdst[NEDGE];
    __shared__ int   setp[NEDGE];
    __shared__ float z[6][DDIM];

    const int* src = ei + (size_t)b * 2 * NEDGE;
    const int* dst = src + NEDGE;
    const int* etb = et + (size_t)b * NEDGE;

    if (t < NNODE * NREL) cnt[t] = 0;
    __syncthreads();
    if (t < NEDGE) {
        int s = src[t], d = dst[t], r = etb[t];
        ssrc[t] = s; sdst[t] = d; setp[t] = r;
        atomicAdd(&cnt[d * NREL + r], 1);
    }
    __syncthreads();
    if (t < NNODE * NREL) dinv[t] = rsqrtf(1.0f + (float)cnt[t]);
    __syncthreads();

    const float* xb = x + (size_t)b * NNODE * DDIM;
    for (int d = t; d < DDIM; d += 256) {
        float x0 = xb[d];
#pragma unroll
        for (int r = 0; r < NREL; r++) { float c = dinv[r]; z[r][d] = c * c * x0; }
        z[5][d] = x0;
    }
    __syncthreads();
    for (int e = 0; e < NEDGE; e++) {
        if (sdst[e] != 0) continue;
        int s = ssrc[e], r = setp[e];
        float coeff = dinv[s * NREL + r] * dinv[r];
        const float* xs = xb + (size_t)s * DDIM;
        for (int d = t; d < DDIM; d += 256) z[r][d] += coeff * xs[d];
    }
    __syncthreads();
    unsigned short* zo = Zb + (size_t)b * K1PAD;
    for (int k = t; k < K1PAD; k += 256) {
        unsigned short v = 0;
        if (k < 6 * DDIM) { int r = k / DDIM, d = k - r * DDIM; v = f2bf(z[r][d]); }
        zo[k] = v;
    }
}

// ---------------------------------------------------------------------------
// K2: stacked conv weights -> bf16 B[n][k], zero padded; 384 rows x K1PAD.
__global__ __launch_bounds__(256) void k_prep_w(
    const float* __restrict__ convW, const float* __restrict__ W0f,
    unsigned short* __restrict__ Wcb)
{
    int idx = blockIdx.x * 256 + threadIdx.x;
    if (idx >= 384 * K1PAD) return;
    int n = idx / K1PAD, k = idx - n * K1PAD;
    float v = 0.f;
    if (n < DDIM && k < 6 * DDIM) {
        int r = k / DDIM, d = k - r * DDIM;
        v = (r < NREL) ? convW[((size_t)r * DDIM + d) * DDIM + n]
                       : W0f[(size_t)d * DDIM + n];
    }
    Wcb[idx] = f2bf(v);
}

// ---------------------------------------------------------------------------
// Convert glob_W + sense_W fp32 [V x 300] -> bf16 [WROWS x 320], rows and K
// zero-padded so the GEMM B path needs no bounds checks.
__global__ __launch_bounds__(256) void k_conv_w2(
    const float* __restrict__ globW, const float* __restrict__ senseW,
    unsigned short* __restrict__ Wgb)
{
    int idx = blockIdx.x * 256 + threadIdx.x;      // WROWS*80 threads
    int row = idx / 80, kq = (idx - row * 80) * 4;
    unsigned int p0 = 0, p1 = 0;
    if (kq < DDIM) {
        const float* srcp = nullptr;
        if (row < GROWS) { if (row < VGLOB) srcp = globW + (size_t)row * DDIM; }
        else { int sr = row - GROWS; if (sr < VSENSE) srcp = senseW + (size_t)sr * DDIM; }
        if (srcp) {
            float4 v = *(const float4*)(srcp + kq);
            p0 = (unsigned int)f2bf(v.x) | ((unsigned int)f2bf(v.y) << 16);
            p1 = (unsigned int)f2bf(v.z) | ((unsigned int)f2bf(v.w) << 16);
        }
    }
    uint2 pp; pp.x = p0; pp.y = p1;
    *(uint2*)(Wgb + (size_t)row * K2PAD + kq) = pp;
}

// ---------------------------------------------------------------------------
// bf16 MFMA GEMM, m97-structure: global_load_lds (16B) staging into linear
// LDS holding XOR-swizzled data (swizzle applied on the GLOBAL source addr
// and again on the LDS read — rule #21 both-sides involution).
// Tile 128x128, TILE_K=64 (128-B LDS rows, (row&7)<<4 XOR -> 2-way reads).
// MODE 0: plain store (+split-K via blockIdx.z, partial buffers)
// MODE 1: softmax stats (per-tile row max / sumexp partials)
// MODE 2: store + bias - lse[row]
// For MODE!=0 the (tile,m) pair is remapped from the linear dispatch id so
// the 4 m-replicas of one column tile share an XCD (L2 reuse of the B tile).
template<int MODE>
__global__ __launch_bounds__(256) void k_gemm_b(
    const unsigned short* __restrict__ A, int ldk, int nk, int kchunk,
    int tiles0,
    const unsigned short* __restrict__ B0, int ldb0,
    const float* __restrict__ bias0, float* __restrict__ C0, long ldc0,
    int nstore0, const float* __restrict__ lse0, int tilebase0,
    const unsigned short* __restrict__ B1, int ldb1,
    const float* __restrict__ bias1, float* __restrict__ C1, long ldc1,
    int nstore1, const float* __restrict__ lse1, int tilebase1,
    float* __restrict__ pmax, float* __restrict__ psum)
{
    __shared__ __align__(16) char Alds[128 * 128];   // 128 rows x 128 B
    __shared__ __align__(16) char Blds[128 * 128];

    int t = threadIdx.x;
    int tile, mrep;
    if constexpr (MODE == 0) {
        tile = blockIdx.x; mrep = blockIdx.y;
    } else {
        // dispatch-linear id; group so replicas are i, i+8, i+16, i+24
        int i = blockIdx.x + TGTOT * blockIdx.y;     // 0..2191
        if (i < 2176) { int g = i >> 5, r = i & 31; tile = g * 8 + (r & 7); mrep = r >> 3; }
        else          { int j = i - 2176; tile = 544 + (j & 3); mrep = j >> 2; }
    }

    const unsigned short* Bp; const float *bias, *lse; float* Cout;
    long ldc; int ldb, nstore, tileidx, tloc;
    if (tile < tiles0) {
        Bp = B0; bias = bias0; Cout = C0; lse = lse0; ldc = ldc0;
        ldb = ldb0; nstore = nstore0; tloc = tile; tileidx = tilebase0 + tile;
    } else {
        tloc = tile - tiles0;
        Bp = B1; bias = bias1; Cout = C1; lse = lse1; ldc = ldc1;
        ldb = ldb1; nstore = nstore1; tileidx = tilebase1 + tloc;
    }
    int n0 = tloc * 128;
    int m0 = mrep * 128;

    int kt_lo = 0, kt_hi = nk >> 6;
    if constexpr (MODE == 0) {
        if (kchunk > 0) {
            kt_lo = blockIdx.z * kchunk;
            int hi = kt_lo + kchunk;
            if (hi < kt_hi) kt_hi = hi;
            Cout += (size_t)blockIdx.z * (BDIM * 304);
        }
    }

    int lane = t & 63, wid = t >> 6;
    int wm = wid >> 1, wn = wid & 1;
    int l15 = lane & 15, lq = lane >> 4;

    // staging: thread t feeds LDS linear byte t*16 (+c*4096); that slot's
    // logical (row, slot) wants global element (row, slot ^ ((row&7)<<4)).
    int trow = t >> 3;                                   // 0..31 (+c*32)
    int sb = ((t & 7) << 4) ^ ((trow & 7) << 4);         // c*32 preserves row&7
    const char* Ag = (const char*)A + (size_t)(m0 + trow) * (ldk * 2) + sb;
    const char* Bg = (const char*)Bp + (size_t)(n0 + trow) * (ldb * 2) + sb;
    char* Al = Alds + t * 16;
    char* Bl = Blds + t * 16;
    size_t a32 = (size_t)32 * (ldk * 2);
    size_t b32 = (size_t)32 * (ldb * 2);

    // fragment reads: row = <base>+i*16+l15; swizzle depends only on l15&7
    int sw = (l15 & 7) << 4;
    int aoff0 = (lq * 16) ^ sw;           // ks=0: bytes [lq*16, +16) of row
    int aoff1 = (64 + lq * 16) ^ sw;      // ks=1
    const char* Arow = Alds + (wm * 64 + l15) * 128;
    const char* Brow = Blds + (wn * 64 + l15) * 128;

    f32x4 acc[4][4] = {};

    for (int kt = kt_lo; kt < kt_hi; ++kt) {
        int k0b = kt << 7;                // 128 B per k-step
        const char* Agk = Ag + k0b;
        const char* Bgk = Bg + k0b;
#pragma unroll
        for (int c = 0; c < 4; c++) {
            gload16(Agk + c * a32, Al + c * 4096);
            gload16(Bgk + c * b32, Bl + c * 4096);
        }
        __syncthreads();                  // drains vmcnt(0): LDS tiles ready
        short8 afr[4][2], bfr[4][2];
#pragma unroll
        for (int i = 0; i < 4; i++) {
            const char* Ab = Arow + i * (16 * 128);
            const char* Bb = Brow + i * (16 * 128);
            afr[i][0] = *(const short8*)(Ab + aoff0);
            afr[i][1] = *(const short8*)(Ab + aoff1);
            bfr[i][0] = *(const short8*)(Bb + aoff0);
            bfr[i][1] = *(const short8*)(Bb + aoff1);
        }
#pragma unroll
        for (int ks = 0; ks < 2; ks++)
#pragma unroll
            for (int mi = 0; mi < 4; mi++)
#pragma unroll
                for (int ni = 0; ni < 4; ni++)
                    acc[mi][ni] = __builtin_amdgcn_mfma_f32_16x16x32_bf16(
                        afr[mi][ks], bfr[ni][ks], acc[mi][ni], 0, 0, 0);
        __syncthreads();                  // reads done before next stage
    }

    if constexpr (MODE == 1) {
        __shared__ float sMax[128][2];
        __shared__ float sSum[128][2];
#pragma unroll
        for (int mi = 0; mi < 4; mi++) {
#pragma unroll
            for (int r = 0; r < 4; r++) {
                float vals[4];
                float rowmax = -3.0e38f;
#pragma unroll
                for (int ni = 0; ni < 4; ni++) {
                    int col = n0 + wn * 64 + ni * 16 + l15;
                    float v = -3.0e38f;
                    if (col < nstore) v = acc[mi][ni][r] + bias[col];
                    vals[ni] = v;
                    rowmax = fmaxf(rowmax, v);
                }
#pragma unroll
                for (int off = 1; off < 16; off <<= 1)
                    rowmax = fmaxf(rowmax, __shfl_xor(rowmax, off, 64));
                float s = 0.f;
#pragma unroll
                for (int ni = 0; ni < 4; ni++) s += __expf(vals[ni] - rowmax);
#pragma unroll
                for (int off = 1; off < 16; off <<= 1) s += __shfl_xor(s, off, 64);
                if (l15 == 0) {
                    int rl = wm * 64 + mi * 16 + lq * 4 + r;
                    sMax[rl][wn] = rowmax; sSum[rl][wn] = s;
                }
            }
        }
        __syncthreads();
        if (t < 128) {
            float ma = sMax[t][0], mb = sMax[t][1];
            float M = fmaxf(ma, mb);
            float S = sSum[t][0] * __expf(ma - M) + sSum[t][1] * __expf(mb - M);
            size_t o = (size_t)tileidx * BDIM + (m0 + t);
            pmax[o] = M; psum[o] = S;
        }
    } else {
#pragma unroll
        for (int mi = 0; mi < 4; mi++) {
            int row = m0 + wm * 64 + mi * 16 + lq * 4;
#pragma unroll
            for (int ni = 0; ni < 4; ni++) {
                int col = n0 + wn * 64 + ni * 16 + l15;
                if (col < nstore) {
#pragma unroll
                    for (int r = 0; r < 4; r++) {
                        float v = acc[mi][ni][r];
                        if constexpr (MODE == 2) v += bias[col] - lse[row + r];
                        Cout[(size_t)(row + r) * ldc + col] = v;
                    }
                }
            }
        }
    }
}

// ---------------------------------------------------------------------------
// Fallback GEMM (fp32 B converted in-flight) for small-workspace path.
// Original 128x128 / TILE_K=32 reg-staging structure.
template<int MODE>
__global__ __launch_bounds__(256) void k_gemm_f32(
    const unsigned short* __restrict__ A, int ldk, int nk,
    int tiles0,
    const float* __restrict__ B0, int ldb0, int ksrc0, int brows0,
    const float* __restrict__ bias0, float* __restrict__ C0, long ldc0,
    int nstore0, const float* __restrict__ lse0, int tilebase0,
    const float* __restrict__ B1, int ldb1, int ksrc1, int brows1,
    const float* __restrict__ bias1, float* __restrict__ C1, long ldc1,
    int nstore1, const float* __restrict__ lse1, int tilebase1,
    float* __restrict__ pmax, float* __restrict__ psum)
{
    __shared__ __align__(16) short Alds[128 * 32];
    __shared__ __align__(16) short Blds[128 * 32];

    int t = threadIdx.x;
    int bx = blockIdx.x;
    const float* Bsrc; const float *bias, *lse; float* Cout;
    long ldc; int ldb, ksrc, brows, nstore, tileidx;
    if (bx < tiles0) {
        Bsrc = B0; bias = bias0; Cout = C0; lse = lse0; ldc = ldc0;
        ldb = ldb0; ksrc = ksrc0; brows = brows0; nstore = nstore0;
        tileidx = tilebase0 + bx;
    } else {
        bx -= tiles0;
        Bsrc = B1; bias = bias1; Cout = C1; lse = lse1; ldc = ldc1;
        ldb = ldb1; ksrc = ksrc1; brows = brows1; nstore = nstore1;
        tileidx = tilebase1 + bx;
    }
    int n0 = bx * 128;
    int m0 = blockIdx.y * 128;

    int lane = t & 63, wid = t >> 6;
    int wm = wid >> 1, wn = wid & 1;
    int l15 = lane & 15, lq = lane >> 4;

    f32x4 acc[4][4] = {};

    int arow = t >> 1, acol = (t & 1) * 16;
    const unsigned short* aptr = A + (size_t)(m0 + arow) * ldk + acol;
    int brow = t >> 3, bkq = (t & 7) * 4;

    int kt_hi = nk / 32;
    for (int kt = 0; kt < kt_hi; ++kt) {
        int k0 = kt * 32;
        uint4 a0 = *(const uint4*)(aptr + k0);
        uint4 a1 = *(const uint4*)(aptr + k0 + 8);
        float4 bv[4];
#pragma unroll
        for (int j = 0; j < 4; j++) {
            int row = n0 + brow + 32 * j;
            float4 v = {0.f, 0.f, 0.f, 0.f};
            if (row < brows && (k0 + bkq + 4) <= ksrc)
                v = *(const float4*)(Bsrc + (size_t)row * ldb + k0 + bkq);
            bv[j] = v;
        }
        __syncthreads();
        *(uint4*)&Alds[arow * 32 + acol] = a0;
        *(uint4*)&Alds[arow * 32 + acol + 8] = a1;
#pragma unroll
        for (int j = 0; j < 4; j++) {
            unsigned int p0 = (unsigned int)f2bf(bv[j].x) | ((unsigned int)f2bf(bv[j].y) << 16);
            unsigned int p1 = (unsigned int)f2bf(bv[j].z) | ((unsigned int)f2bf(bv[j].w) << 16);
            uint2 pp; pp.x = p0; pp.y = p1;
            *(uint2*)&Blds[(brow + 32 * j) * 32 + bkq] = pp;
        }
        __syncthreads();
        short8 afr[4], bfr[4];
#pragma unroll
        for (int i = 0; i < 4; i++) {
            afr[i] = *(const short8*)&Alds[(wm * 64 + i * 16 + l15) * 32 + lq * 8];
            bfr[i] = *(const short8*)&Blds[(wn * 64 + i * 16 + l15) * 32 + lq * 8];
        }
#pragma unroll
        for (int mi = 0; mi < 4; mi++)
#pragma unroll
            for (int ni = 0; ni < 4; ni++)
                acc[mi][ni] = __builtin_amdgcn_mfma_f32_16x16x32_bf16(
                    afr[mi], bfr[ni], acc[mi][ni], 0, 0, 0);
    }

    if constexpr (MODE == 1) {
        __shared__ float sMax[128][2];
        __shared__ float sSum[128][2];
#pragma unroll
        for (int mi = 0; mi < 4; mi++) {
#pragma unroll
            for (int r = 0; r < 4; r++) {
                float vals[4];
                float rowmax = -3.0e38f;
#pragma unroll
                for (int ni = 0; ni < 4; ni++) {
                    int col = n0 + wn * 64 + ni * 16 + l15;
                    float v = -3.0e38f;
                    if (col < nstore) v = acc[mi][ni][r] + bias[col];
                    vals[ni] = v;
                    rowmax = fmaxf(rowmax, v);
                }
#pragma unroll
                for (int off = 1; off < 16; off <<= 1)
                    rowmax = fmaxf(rowmax, __shfl_xor(rowmax, off, 64));
                float s = 0.f;
#pragma unroll
                for (int ni = 0; ni < 4; ni++) s += __expf(vals[ni] - rowmax);
#pragma unroll
                for (int off = 1; off < 16; off <<= 1) s += __shfl_xor(s, off, 64);
                if (l15 == 0) {
                    int rl = wm * 64 + mi * 16 + lq * 4 + r;
                    sMax[rl][wn] = rowmax; sSum[rl][wn] = s;
                }
            }
        }
        __syncthreads();
        if (t < 128) {
            float ma = sMax[t][0], mb = sMax[t][1];
            float M = fmaxf(ma, mb);
            float S = sSum[t][0] * __expf(ma - M) + sSum[t][1] * __expf(mb - M);
            size_t o = (size_t)tileidx * BDIM + (m0 + t);
            pmax[o] = M; psum[o] = S;
        }
    } else {
#pragma unroll
        for (int mi = 0; mi < 4; mi++) {
            int row = m0 + wm * 64 + mi * 16 + lq * 4;
#pragma unroll
            for (int ni = 0; ni < 4; ni++) {
                int col = n0 + wn * 64 + ni * 16 + l15;
                if (col < nstore) {
#pragma unroll
                    for (int r = 0; r < 4; r++) {
                        float v = acc[mi][ni][r];
                        if constexpr (MODE == 2) v += bias[col] - lse[row + r];
                        Cout[(size_t)(row + r) * ldc + col] = v;
                    }
                }
            }
        }
    }
}

// ---------------------------------------------------------------------------
// Gate recurrence as affine scan; sums NCHUNK split-K partials on the fly.
// 16 chunks of 32 steps (2x the parallelism of the old 8x64 split).
__global__ __launch_bounds__(320) void k_scan_local(
    const float* __restrict__ prop, float* __restrict__ scanA,
    const float* __restrict__ gate)
{
    int d = threadIdx.x; if (d >= 304) return;
    int blk = blockIdx.x;
    float g = gate[0], og = 1.f - g;
    float m = 0.f;
    const float* p0 = prop + (size_t)blk * SCHL * 304 + d;
    const float* p1 = p0 + (size_t)BDIM * 304;
    const float* p2 = p1 + (size_t)BDIM * 304;
    float* o = scanA + (size_t)blk * SCHL * 304 + d;
#pragma unroll
    for (int i = 0; i < SCHL; i++) {
        size_t off = (size_t)i * 304;
        float pv = p0[off] + p1[off] + p2[off];
        m = g * pv + og * m;
        o[off] = m;
    }
}

__global__ __launch_bounds__(320) void k_scan_combine(
    const float* __restrict__ scanA, const float* __restrict__ gate,
    const float* __restrict__ mem0, float* __restrict__ mstart)
{
    int d = threadIdx.x; if (d >= DDIM) return;
    float g = gate[0], og = 1.f - g;
    float cS = powi(og, SCHL);
    float m = mem0[d];
#pragma unroll
    for (int blk = 0; blk < NSCH; blk++) {
        mstart[blk * 304 + d] = m;
        m = scanA[(size_t)(blk * SCHL + SCHL - 1) * 304 + d] + cS * m;
    }
}

__global__ __launch_bounds__(320) void k_finalize_x1(
    const float* __restrict__ scanA, const float* __restrict__ mstart,
    const float* __restrict__ gate, unsigned short* __restrict__ x1b)
{
    int b = blockIdx.x, d = threadIdx.x;
    unsigned short v = 0;
    if (d < DDIM) {
        float g = gate[0], og = 1.f - g;
        float mval = scanA[(size_t)b * 304 + d]
                   + powi(og, (b & (SCHL - 1)) + 1) * mstart[(b >> 5) * 304 + d];
        v = f2bf(fmaxf(mval, 0.f));
    }
    if (d < K2PAD) x1b[(size_t)b * K2PAD + d] = v;
}

// ---------------------------------------------------------------------------
// Parallel lse: one block per (b, seg); thread-local online merge -> wave
// shuffle merge -> cross-wave LDS merge.
__global__ __launch_bounds__(256) void k_lse_par(
    const float* __restrict__ pmax, const float* __restrict__ psum,
    float* __restrict__ lse)
{
    int b = blockIdx.x, seg = blockIdx.y, t = threadIdx.x;
    int base = seg ? TG_GLOB : 0;
    int nt = seg ? TG_SENSE : TG_GLOB;
    float M = -3.0e38f, S = 0.f;
    for (int i = t; i < nt; i += 256) {
        size_t o = (size_t)(base + i) * BDIM + b;
        float m = pmax[o], s = psum[o];
        if (m > M) { S = S * __expf(M - m) + s; M = m; }
        else       { S += s * __expf(m - M); }
    }
#pragma unroll
    for (int off = 1; off < 64; off <<= 1) {
        float Mo = __shfl_xor(M, off, 64), So = __shfl_xor(S, off, 64);
        float Mn = fmaxf(M, Mo);
        S = S * __expf(M - Mn) + So * __expf(Mo - Mn);
        M = Mn;
    }
    __shared__ float sM[4], sS[4];
    int lane = t & 63, wid = t >> 6;
    if (lane == 0) { sM[wid] = M; sS[wid] = S; }
    __syncthreads();
    if (t == 0) {
        M = sM[0]; S = sS[0];
#pragma unroll
        for (int w = 1; w < 4; w++) {
            float Mo = sM[w], So = sS[w];
            float Mn = fmaxf(M, Mo);
            S = S * __expf(M - Mn) + So * __expf(Mo - Mn);
            M = Mn;
        }
        lse[seg * BDIM + b] = M + __logf(S);
    }
}

// ---------------------------------------------------------------------------
extern "C" void kernel_launch(void* const* d_in, const int* in_sizes, int n_in,
                              void* d_out, int out_size, void* d_ws, size_t ws_size,
                              hipStream_t stream)
{
    (void)in_sizes; (void)n_in; (void)out_size;
    const float* x      = (const float*)d_in[0];
    const int*   ei     = (const int*)d_in[1];
    const int*   et     = (const int*)d_in[2];
    const float* convW  = (const float*)d_in[3];
    const float* W0f    = (const float*)d_in[4];
    const float* gate   = (const float*)d_in[5];
    const float* globW  = (const float*)d_in[6];
    const float* globB  = (const float*)d_in[7];
    const float* senseW = (const float*)d_in[8];
    const float* senseB = (const float*)d_in[9];
    const float* mem0   = (const float*)d_in[10];
    float* out = (float*)d_out;

    // workspace layout (base ~8.4 MB; bf16 vocab weights above that)
    char* w = (char*)d_ws;
    unsigned short* Zb  = (unsigned short*)(w + 0);          // 512*1856*2 = 1900544
    unsigned short* Wcb = (unsigned short*)(w + 1900544);    // 384*1856*2 = 1425408
    unsigned short* x1b = (unsigned short*)(w + 3325952);    // 512*320*2  = 327680
    float* prop         = (float*)(w + 3653632);             // 3*512*304*4= 1867776
    float* scanA        = (float*)(w + 5521408);             // 512*304*4  = 622592
    float* mstart       = (float*)(w + 6144000);             // 16*304*4   = 19456
    float* pmax         = (float*)(w + 6163456);             // 548*512*4  = 1122304
    float* psum         = (float*)(w + 7285760);             // 548*512*4  = 1122304
    float* lse          = (float*)(w + 8408064);             // 2*512*4    = 4096
    unsigned short* Wgb = (unsigned short*)(w + 8412160);    // 70144*320*2= 44892160
    const size_t WS_NEED_BIG = 8412160 + (size_t)WROWS * K2PAD * 2;  // ~53.3 MB
    bool bigws = ws_size >= WS_NEED_BIG;

    k_prep_z<<<BDIM, 256, 0, stream>>>(x, ei, et, Zb);
    k_prep_w<<<(384 * K1PAD + 255) / 256, 256, 0, stream>>>(convW, W0f, Wcb);
    if (bigws)
        k_conv_w2<<<(WROWS * 80) / 256, 256, 0, stream>>>(globW, senseW, Wgb);

    // stage-1: prop[z][512 x 304] partials = Zb . Wcb^T (split-K, 36 blocks)
    k_gemm_b<0><<<dim3(3, 4, NCHUNK), 256, 0, stream>>>(Zb, K1PAD, K1PAD, KCH,
        3, Wcb, K1PAD, nullptr, prop, 304, 304, nullptr, 0,
        nullptr, 0, nullptr, nullptr, 0, 0, nullptr, 0,
        nullptr, nullptr);

    k_scan_local<<<NSCH, 320, 0, stream>>>(prop, scanA, gate);
    k_scan_combine<<<1, 320, 0, stream>>>(scanA, gate, mem0, mstart);
    k_finalize_x1<<<BDIM, 320, 0, stream>>>(scanA, mstart, gate, x1b);

    if (bigws) {
        const unsigned short* WgbS = Wgb + (size_t)GROWS * K2PAD;
        k_gemm_b<1><<<dim3(TGTOT, 4), 256, 0, stream>>>(x1b, K2PAD, K2PAD, 0,
            TG_GLOB, Wgb, K2PAD, globB, nullptr, 0, VGLOB, nullptr, 0,
            WgbS, K2PAD, senseB, nullptr, 0, VSENSE, nullptr, TG_GLOB,
            pmax, psum);
        k_lse_par<<<dim3(BDIM, 2), 256, 0, stream>>>(pmax, psum, lse);
        k_gemm_b<2><<<dim3(TGTOT, 4), 256, 0, stream>>>(x1b, K2PAD, K2PAD, 0,
            TG_GLOB, Wgb, K2PAD, globB, out, VGLOB, VGLOB, lse, 0,
            WgbS, K2PAD, senseB, out + (size_t)BDIM * VGLOB, VSENSE, VSENSE, lse + BDIM, 0,
            nullptr, nullptr);
    } else {
        k_gemm_f32<1><<<dim3(TGTOT, 4), 256, 0, stream>>>(x1b, K2PAD, K2PAD,
            TG_GLOB, globW, DDIM, DDIM, VGLOB, globB, nullptr, 0, VGLOB, nullptr, 0,
            senseW, DDIM, DDIM, VSENSE, senseB, nullptr, 0, VSENSE, nullptr, TG_GLOB,
            pmax, psum);
        k_lse_par<<<dim3(BDIM, 2), 256, 0, stream>>>(pmax, psum, lse);
        k_gemm_f32<2><<<dim3(TGTOT, 4), 256, 0, stream>>>(x1b, K2PAD, K2PAD,
            TG_GLOB, globW, DDIM, DDIM, VGLOB, globB, out, VGLOB, VGLOB, lse, 0,
            senseW, DDIM, DDIM, VSENSE, senseB, out + (size_t)BDIM * VGLOB, VSENSE, VSENSE, lse + BDIM, 0,
            nullptr, nullptr);
    }
}

// Round 2
// 389.554 us; speedup vs baseline: 1.0927x; 1.0043x over previous
//
#include <hip/hip_runtime.h>
#include <stdint.h>

// Problem constants
#define BDIM   512
#define NNODE  32
#define DDIM   300
#define NREL   5
#define NEDGE  256
#define VGLOB  50000
#define VSENSE 20000

#define K1PAD  1856   // stage-1 K: 6*300=1800 padded to 29*64
#define K2PAD  320    // stage-2 K: 300 padded to 5*64
#define TG_GLOB  391  // ceil(50000/128)
#define TG_SENSE 157  // ceil(20000/128)
#define TGTOT  548
#define GROWS  50048  // 391*128 padded rows
#define SROWS  20096  // 157*128
#define WROWS  70144  // GROWS+SROWS
#define NCHUNK 3      // stage-1 split-K chunks
#define KCH    10     // 64-wide k-steps per chunk (10+10+9 = 29)
#define NSCH   16     // scan chunks
#define SCHL   32     // scan chunk length

#define NB_W2  21920  // WROWS*80/256 conv_w2 blocks
#define NB_Z   512
#define NB_W   2784   // 384*K1PAD/256

typedef __attribute__((ext_vector_type(8))) short short8;
typedef __attribute__((ext_vector_type(4))) float f32x4;

__device__ __forceinline__ unsigned short f2bf(float x) {
    unsigned int u = __float_as_uint(x);
    u += 0x7fffu + ((u >> 16) & 1u);   // RNE
    return (unsigned short)(u >> 16);
}

__device__ __forceinline__ float powi(float x, int n) {
    float r = 1.f, p = x;
    while (n) { if (n & 1) r *= p; p *= p; n >>= 1; }
    return r;
}

#define AS1 __attribute__((address_space(1)))
#define AS3 __attribute__((address_space(3)))
__device__ __forceinline__ void gload16(const void* gp, void* lp) {
    __builtin_amdgcn_global_load_lds((AS1 void*)gp, (AS3 void*)lp, 16, 0, 0);
}

// ---------------------------------------------------------------------------
// Fused prep: blocks [0,zbase) convert vocab weights to bf16 (bigws only),
// [zbase, zbase+512) per-batch graph prep, rest stack conv weights.
// Conv_w2 blocks first so the 129 MB stream starts immediately; the small
// graph/weight prep rides along concurrently instead of as serial dispatches.
__global__ __launch_bounds__(256) void k_prep_all(
    const float* __restrict__ x, const int* __restrict__ ei,
    const int* __restrict__ et, unsigned short* __restrict__ Zb,
    const float* __restrict__ convW, const float* __restrict__ W0f,
    unsigned short* __restrict__ Wcb,
    const float* __restrict__ globW, const float* __restrict__ senseW,
    unsigned short* __restrict__ Wgb, int zbase)
{
    int blk = blockIdx.x, t = threadIdx.x;

    if (blk < zbase) {
        // ---- conv_w2: fp32 vocab weights -> bf16 [WROWS x 320]
        int idx = blk * 256 + t;
        int row = idx / 80, kq = (idx - row * 80) * 4;
        unsigned int p0 = 0, p1 = 0;
        if (kq < DDIM) {
            const float* srcp = nullptr;
            if (row < GROWS) { if (row < VGLOB) srcp = globW + (size_t)row * DDIM; }
            else { int sr = row - GROWS; if (sr < VSENSE) srcp = senseW + (size_t)sr * DDIM; }
            if (srcp) {
                float4 v = *(const float4*)(srcp + kq);
                p0 = (unsigned int)f2bf(v.x) | ((unsigned int)f2bf(v.y) << 16);
                p1 = (unsigned int)f2bf(v.z) | ((unsigned int)f2bf(v.w) << 16);
            }
        }
        uint2 pp; pp.x = p0; pp.y = p1;
        *(uint2*)(Wgb + (size_t)row * K2PAD + kq) = pp;
        return;
    }

    if (blk < zbase + NB_Z) {
        // ---- prep_z: per-batch graph prep -> Z[b, k] bf16
        int b = blk - zbase;
        __shared__ int   cnt[NNODE * NREL];
        __shared__ float dinv[NNODE * NREL];
        __shared__ int   ssrc[NEDGE];
        __shared__ int   sdst[NEDGE];
        __shared__ int   setp[NEDGE];
        __shared__ float z[6][DDIM];

        const int* src = ei + (size_t)b * 2 * NEDGE;
        const int* dst = src + NEDGE;
        const int* etb = et + (size_t)b * NEDGE;

        if (t < NNODE * NREL) cnt[t] = 0;
        __syncthreads();
        if (t < NEDGE) {
            int s = src[t], d = dst[t], r = etb[t];
            ssrc[t] = s; sdst[t] = d; setp[t] = r;
            atomicAdd(&cnt[d * NREL + r], 1);
        }
        __syncthreads();
        if (t < NNODE * NREL) dinv[t] = rsqrtf(1.0f + (float)cnt[t]);
        __syncthreads();

        const float* xb = x + (size_t)b * NNODE * DDIM;
        for (int d = t; d < DDIM; d += 256) {
            float x0 = xb[d];
#pragma unroll
            for (int r = 0; r < NREL; r++) { float c = dinv[r]; z[r][d] = c * c * x0; }
            z[5][d] = x0;
        }
        __syncthreads();
        for (int e = 0; e < NEDGE; e++) {
            if (sdst[e] != 0) continue;
            int s = ssrc[e], r = setp[e];
            float coeff = dinv[s * NREL + r] * dinv[r];
            const float* xs = xb + (size_t)s * DDIM;
            for (int d = t; d < DDIM; d += 256) z[r][d] += coeff * xs[d];
        }
        __syncthreads();
        unsigned short* zo = Zb + (size_t)b * K1PAD;
        for (int k = t; k < K1PAD; k += 256) {
            unsigned short v = 0;
            if (k < 6 * DDIM) { int r = k / DDIM, d = k - r * DDIM; v = f2bf(z[r][d]); }
            zo[k] = v;
        }
        return;
    }

    // ---- prep_w: stacked conv weights -> bf16 [384 x K1PAD]
    {
        int idx = (blk - zbase - NB_Z) * 256 + t;
        if (idx >= 384 * K1PAD) return;
        int n = idx / K1PAD, k = idx - n * K1PAD;
        float v = 0.f;
        if (n < DDIM && k < 6 * DDIM) {
            int r = k / DDIM, d = k - r * DDIM;
            v = (r < NREL) ? convW[((size_t)r * DDIM + d) * DDIM + n]
                           : W0f[(size_t)d * DDIM + n];
        }
        Wcb[idx] = f2bf(v);
    }
}

// ---------------------------------------------------------------------------
// bf16 MFMA GEMM, m97-structure: global_load_lds (16B) staging into linear
// LDS holding XOR-swizzled data (swizzle on the GLOBAL source addr and again
// on the LDS read — both-sides involution). Tile 128x128, TILE_K=64.
// MODE 0: plain store (+split-K via blockIdx.z, partial buffers)
// MODE 1: store acc+bias to C AND emit per-tile softmax stats (pmax/psum).
// For MODE 1 the (tile,m) pair is remapped from the linear dispatch id so
// the 4 m-replicas of one column tile share an XCD (L2 reuse of the B tile).
template<int MODE>
__global__ __launch_bounds__(256) void k_gemm_b(
    const unsigned short* __restrict__ A, int ldk, int nk, int kchunk,
    int tiles0,
    const unsigned short* __restrict__ B0, int ldb0,
    const float* __restrict__ bias0, float* __restrict__ C0, long ldc0,
    int nstore0, int tilebase0,
    const unsigned short* __restrict__ B1, int ldb1,
    const float* __restrict__ bias1, float* __restrict__ C1, long ldc1,
    int nstore1, int tilebase1,
    float* __restrict__ pmax, float* __restrict__ psum)
{
    __shared__ __align__(16) char Alds[128 * 128];   // 128 rows x 128 B
    __shared__ __align__(16) char Blds[128 * 128];

    int t = threadIdx.x;
    int tile, mrep;
    if constexpr (MODE == 0) {
        tile = blockIdx.x; mrep = blockIdx.y;
    } else {
        // dispatch-linear id; group so replicas are i, i+8, i+16, i+24
        int i = blockIdx.x + TGTOT * blockIdx.y;     // 0..2191
        if (i < 2176) { int g = i >> 5, r = i & 31; tile = g * 8 + (r & 7); mrep = r >> 3; }
        else          { int j = i - 2176; tile = 544 + (j & 3); mrep = j >> 2; }
    }

    const unsigned short* Bp; const float* bias; float* Cout;
    long ldc; int ldb, nstore, tileidx, tloc;
    if (tile < tiles0) {
        Bp = B0; bias = bias0; Cout = C0; ldc = ldc0;
        ldb = ldb0; nstore = nstore0; tloc = tile; tileidx = tilebase0 + tile;
    } else {
        tloc = tile - tiles0;
        Bp = B1; bias = bias1; Cout = C1; ldc = ldc1;
        ldb = ldb1; nstore = nstore1; tileidx = tilebase1 + tloc;
    }
    int n0 = tloc * 128;
    int m0 = mrep * 128;

    int kt_lo = 0, kt_hi = nk >> 6;
    if constexpr (MODE == 0) {
        if (kchunk > 0) {
            kt_lo = blockIdx.z * kchunk;
            int hi = kt_lo + kchunk;
            if (hi < kt_hi) kt_hi = hi;
            Cout += (size_t)blockIdx.z * (BDIM * 304);
        }
    }

    int lane = t & 63, wid = t >> 6;
    int wm = wid >> 1, wn = wid & 1;
    int l15 = lane & 15, lq = lane >> 4;

    // staging: thread t feeds LDS linear byte t*16 (+c*4096); that slot's
    // logical (row, slot) wants global element (row, slot ^ ((row&7)<<4)).
    int trow = t >> 3;                                   // 0..31 (+c*32)
    int sb = ((t & 7) << 4) ^ ((trow & 7) << 4);         // c*32 preserves row&7
    const char* Ag = (const char*)A + (size_t)(m0 + trow) * (ldk * 2) + sb;
    const char* Bg = (const char*)Bp + (size_t)(n0 + trow) * (ldb * 2) + sb;
    char* Al = Alds + t * 16;
    char* Bl = Blds + t * 16;
    size_t a32 = (size_t)32 * (ldk * 2);
    size_t b32 = (size_t)32 * (ldb * 2);

    // fragment reads: row = <base>+i*16+l15; swizzle depends only on l15&7
    int sw = (l15 & 7) << 4;
    int aoff0 = (lq * 16) ^ sw;           // ks=0: bytes [lq*16, +16) of row
    int aoff1 = (64 + lq * 16) ^ sw;      // ks=1
    const char* Arow = Alds + (wm * 64 + l15) * 128;
    const char* Brow = Blds + (wn * 64 + l15) * 128;

    f32x4 acc[4][4] = {};

    for (int kt = kt_lo; kt < kt_hi; ++kt) {
        int k0b = kt << 7;                // 128 B per k-step
        const char* Agk = Ag + k0b;
        const char* Bgk = Bg + k0b;
#pragma unroll
        for (int c = 0; c < 4; c++) {
            gload16(Agk + c * a32, Al + c * 4096);
            gload16(Bgk + c * b32, Bl + c * 4096);
        }
        __syncthreads();                  // drains vmcnt(0): LDS tiles ready
        short8 afr[4][2], bfr[4][2];
#pragma unroll
        for (int i = 0; i < 4; i++) {
            const char* Ab = Arow + i * (16 * 128);
            const char* Bb = Brow + i * (16 * 128);
            afr[i][0] = *(const short8*)(Ab + aoff0);
            afr[i][1] = *(const short8*)(Ab + aoff1);
            bfr[i][0] = *(const short8*)(Bb + aoff0);
            bfr[i][1] = *(const short8*)(Bb + aoff1);
        }
#pragma unroll
        for (int ks = 0; ks < 2; ks++)
#pragma unroll
            for (int mi = 0; mi < 4; mi++)
#pragma unroll
                for (int ni = 0; ni < 4; ni++)
                    acc[mi][ni] = __builtin_amdgcn_mfma_f32_16x16x32_bf16(
                        afr[mi][ks], bfr[ni][ks], acc[mi][ni], 0, 0, 0);
        __syncthreads();                  // reads done before next stage
    }

    if constexpr (MODE == 1) {
        __shared__ float sMax[128][2];
        __shared__ float sSum[128][2];
#pragma unroll
        for (int mi = 0; mi < 4; mi++) {
            int row = m0 + wm * 64 + mi * 16 + lq * 4;
#pragma unroll
            for (int r = 0; r < 4; r++) {
                float vals[4];
                float rowmax = -3.0e38f;
#pragma unroll
                for (int ni = 0; ni < 4; ni++) {
                    int col = n0 + wn * 64 + ni * 16 + l15;
                    float v = -3.0e38f;
                    if (col < nstore) v = acc[mi][ni][r] + bias[col];
                    vals[ni] = v;
                    rowmax = fmaxf(rowmax, v);
                }
                // store logits (acc+bias); lse subtracted later in k_lse_fix
#pragma unroll
                for (int ni = 0; ni < 4; ni++) {
                    int col = n0 + wn * 64 + ni * 16 + l15;
                    if (col < nstore) Cout[(size_t)(row + r) * ldc + col] = vals[ni];
                }
#pragma unroll
                for (int off = 1; off < 16; off <<= 1)
                    rowmax = fmaxf(rowmax, __shfl_xor(rowmax, off, 64));
                float s = 0.f;
#pragma unroll
                for (int ni = 0; ni < 4; ni++) s += __expf(vals[ni] - rowmax);
#pragma unroll
                for (int off = 1; off < 16; off <<= 1) s += __shfl_xor(s, off, 64);
                if (l15 == 0) {
                    int rl = wm * 64 + mi * 16 + lq * 4 + r;
                    sMax[rl][wn] = rowmax; sSum[rl][wn] = s;
                }
            }
        }
        __syncthreads();
        if (t < 128) {
            float ma = sMax[t][0], mb = sMax[t][1];
            float M = fmaxf(ma, mb);
            float S = sSum[t][0] * __expf(ma - M) + sSum[t][1] * __expf(mb - M);
            size_t o = (size_t)tileidx * BDIM + (m0 + t);
            pmax[o] = M; psum[o] = S;
        }
    } else {
#pragma unroll
        for (int mi = 0; mi < 4; mi++) {
            int row = m0 + wm * 64 + mi * 16 + lq * 4;
#pragma unroll
            for (int ni = 0; ni < 4; ni++) {
                int col = n0 + wn * 64 + ni * 16 + l15;
                if (col < nstore) {
#pragma unroll
                    for (int r = 0; r < 4; r++)
                        Cout[(size_t)(row + r) * ldc + col] = acc[mi][ni][r];
                }
            }
        }
    }
}

// ---------------------------------------------------------------------------
// Fallback GEMM (fp32 B converted in-flight) for small-workspace path:
// store acc+bias to C and emit per-tile softmax stats.
__global__ __launch_bounds__(256) void k_gemm_f32(
    const unsigned short* __restrict__ A, int ldk, int nk,
    int tiles0,
    const float* __restrict__ B0, int ldb0, int ksrc0, int brows0,
    const float* __restrict__ bias0, float* __restrict__ C0, long ldc0,
    int nstore0, int tilebase0,
    const float* __restrict__ B1, int ldb1, int ksrc1, int brows1,
    const float* __restrict__ bias1, float* __restrict__ C1, long ldc1,
    int nstore1, int tilebase1,
    float* __restrict__ pmax, float* __restrict__ psum)
{
    __shared__ __align__(16) short Alds[128 * 32];
    __shared__ __align__(16) short Blds[128 * 32];

    int t = threadIdx.x;
    int bx = blockIdx.x;
    const float* Bsrc; const float* bias; float* Cout;
    long ldc; int ldb, ksrc, brows, nstore, tileidx;
    if (bx < tiles0) {
        Bsrc = B0; bias = bias0; Cout = C0; ldc = ldc0;
        ldb = ldb0; ksrc = ksrc0; brows = brows0; nstore = nstore0;
        tileidx = tilebase0 + bx;
    } else {
        bx -= tiles0;
        Bsrc = B1; bias = bias1; Cout = C1; ldc = ldc1;
        ldb = ldb1; ksrc = ksrc1; brows = brows1; nstore = nstore1;
        tileidx = tilebase1 + bx;
    }
    int n0 = bx * 128;
    int m0 = blockIdx.y * 128;

    int lane = t & 63, wid = t >> 6;
    int wm = wid >> 1, wn = wid & 1;
    int l15 = lane & 15, lq = lane >> 4;

    f32x4 acc[4][4] = {};

    int arow = t >> 1, acol = (t & 1) * 16;
    const unsigned short* aptr = A + (size_t)(m0 + arow) * ldk + acol;
    int brow = t >> 3, bkq = (t & 7) * 4;

    int kt_hi = nk / 32;
    for (int kt = 0; kt < kt_hi; ++kt) {
        int k0 = kt * 32;
        uint4 a0 = *(const uint4*)(aptr + k0);
        uint4 a1 = *(const uint4*)(aptr + k0 + 8);
        float4 bv[4];
#pragma unroll
        for (int j = 0; j < 4; j++) {
            int row = n0 + brow + 32 * j;
            float4 v = {0.f, 0.f, 0.f, 0.f};
            if (row < brows && (k0 + bkq + 4) <= ksrc)
                v = *(const float4*)(Bsrc + (size_t)row * ldb + k0 + bkq);
            bv[j] = v;
        }
        __syncthreads();
        *(uint4*)&Alds[arow * 32 + acol] = a0;
        *(uint4*)&Alds[arow * 32 + acol + 8] = a1;
#pragma unroll
        for (int j = 0; j < 4; j++) {
            unsigned int p0 = (unsigned int)f2bf(bv[j].x) | ((unsigned int)f2bf(bv[j].y) << 16);
            unsigned int p1 = (unsigned int)f2bf(bv[j].z) | ((unsigned int)f2bf(bv[j].w) << 16);
            uint2 pp; pp.x = p0; pp.y = p1;
            *(uint2*)&Blds[(brow + 32 * j) * 32 + bkq] = pp;
        }
        __syncthreads();
        short8 afr[4], bfr[4];
#pragma unroll
        for (int i = 0; i < 4; i++) {
            afr[i] = *(const short8*)&Alds[(wm * 64 + i * 16 + l15) * 32 + lq * 8];
            bfr[i] = *(const short8*)&Blds[(wn * 64 + i * 16 + l15) * 32 + lq * 8];
        }
#pragma unroll
        for (int mi = 0; mi < 4; mi++)
#pragma unroll
            for (int ni = 0; ni < 4; ni++)
                acc[mi][ni] = __builtin_amdgcn_mfma_f32_16x16x32_bf16(
                    afr[mi], bfr[ni], acc[mi][ni], 0, 0, 0);
    }

    __shared__ float sMax[128][2];
    __shared__ float sSum[128][2];
#pragma unroll
    for (int mi = 0; mi < 4; mi++) {
        int row = m0 + wm * 64 + mi * 16 + lq * 4;
#pragma unroll
        for (int r = 0; r < 4; r++) {
            float vals[4];
            float rowmax = -3.0e38f;
#pragma unroll
            for (int ni = 0; ni < 4; ni++) {
                int col = n0 + wn * 64 + ni * 16 + l15;
                float v = -3.0e38f;
                if (col < nstore) v = acc[mi][ni][r] + bias[col];
                vals[ni] = v;
                rowmax = fmaxf(rowmax, v);
            }
#pragma unroll
            for (int ni = 0; ni < 4; ni++) {
                int col = n0 + wn * 64 + ni * 16 + l15;
                if (col < nstore) Cout[(size_t)(row + r) * ldc + col] = vals[ni];
            }
#pragma unroll
            for (int off = 1; off < 16; off <<= 1)
                rowmax = fmaxf(rowmax, __shfl_xor(rowmax, off, 64));
            float s = 0.f;
#pragma unroll
            for (int ni = 0; ni < 4; ni++) s += __expf(vals[ni] - rowmax);
#pragma unroll
            for (int off = 1; off < 16; off <<= 1) s += __shfl_xor(s, off, 64);
            if (l15 == 0) {
                int rl = wm * 64 + mi * 16 + lq * 4 + r;
                sMax[rl][wn] = rowmax; sSum[rl][wn] = s;
            }
        }
    }
    __syncthreads();
    if (t < 128) {
        float ma = sMax[t][0], mb = sMax[t][1];
        float M = fmaxf(ma, mb);
        float S = sSum[t][0] * __expf(ma - M) + sSum[t][1] * __expf(mb - M);
        size_t o = (size_t)tileidx * BDIM + (m0 + t);
        pmax[o] = M; psum[o] = S;
    }
}

// ---------------------------------------------------------------------------
// Gate recurrence as affine scan; sums NCHUNK split-K partials on the fly.
__global__ __launch_bounds__(320) void k_scan_local(
    const float* __restrict__ prop, float* __restrict__ scanA,
    const float* __restrict__ gate)
{
    int d = threadIdx.x; if (d >= 304) return;
    int blk = blockIdx.x;
    float g = gate[0], og = 1.f - g;
    float m = 0.f;
    const float* p0 = prop + (size_t)blk * SCHL * 304 + d;
    const float* p1 = p0 + (size_t)BDIM * 304;
    const float* p2 = p1 + (size_t)BDIM * 304;
    float* o = scanA + (size_t)blk * SCHL * 304 + d;
#pragma unroll
    for (int i = 0; i < SCHL; i++) {
        size_t off = (size_t)i * 304;
        float pv = p0[off] + p1[off] + p2[off];
        m = g * pv + og * m;
        o[off] = m;
    }
}

// Finalize x1: each block folds the chunk-end prefix itself (loads are
// independent; only the fma chain is serial) — kills the 1-block combine
// kernel and its serialization point.
__global__ __launch_bounds__(320) void k_finalize_x1(
    const float* __restrict__ scanA, const float* __restrict__ mem0,
    const float* __restrict__ gate, unsigned short* __restrict__ x1b)
{
    int b = blockIdx.x, d = threadIdx.x;
    unsigned short v = 0;
    if (d < DDIM) {
        float g = gate[0], og = 1.f - g;
        float cS = powi(og, SCHL);
        int chunk = b >> 5;
        float m = mem0[d];
        for (int c = 0; c < chunk; c++)
            m = scanA[(size_t)(c * SCHL + SCHL - 1) * 304 + d] + cS * m;
        float mval = scanA[(size_t)b * 304 + d]
                   + powi(og, (b & (SCHL - 1)) + 1) * m;
        v = f2bf(fmaxf(mval, 0.f));
    }
    if (d < K2PAD) x1b[(size_t)b * K2PAD + d] = v;
}

// ---------------------------------------------------------------------------
// Fused lse + fixup: block (b,seg) reduces its row's per-tile stats to lse,
// then immediately rewrites its own output row (out -= lse). No lse buffer,
// no extra dispatch.
__global__ __launch_bounds__(256) void k_lse_fix(
    const float* __restrict__ pmax, const float* __restrict__ psum,
    float* __restrict__ out)
{
    int b = blockIdx.x, seg = blockIdx.y, t = threadIdx.x;
    int base = seg ? TG_GLOB : 0;
    int nt = seg ? TG_SENSE : TG_GLOB;
    float M = -3.0e38f, S = 0.f;
    for (int i = t; i < nt; i += 256) {
        size_t o = (size_t)(base + i) * BDIM + b;
        float m = pmax[o], s = psum[o];
        if (m > M) { S = S * __expf(M - m) + s; M = m; }
        else       { S += s * __expf(m - M); }
    }
#pragma unroll
    for (int off = 1; off < 64; off <<= 1) {
        float Mo = __shfl_xor(M, off, 64), So = __shfl_xor(S, off, 64);
        float Mn = fmaxf(M, Mo);
        S = S * __expf(M - Mn) + So * __expf(Mo - Mn);
        M = Mn;
    }
    __shared__ float sM[4], sS[4];
    __shared__ float sL;
    int lane = t & 63, wid = t >> 6;
    if (lane == 0) { sM[wid] = M; sS[wid] = S; }
    __syncthreads();
    if (t == 0) {
        M = sM[0]; S = sS[0];
#pragma unroll
        for (int w = 1; w < 4; w++) {
            float Mo = sM[w], So = sS[w];
            float Mn = fmaxf(M, Mo);
            S = S * __expf(M - Mn) + So * __expf(Mo - Mn);
            M = Mn;
        }
        sL = M + __logf(S);
    }
    __syncthreads();
    float L = sL;
    float* row = seg ? out + (size_t)BDIM * VGLOB + (size_t)b * VSENSE
                     : out + (size_t)b * VGLOB;
    int n4 = (seg ? VSENSE : VGLOB) >> 2;
    float4* r4 = (float4*)row;
    for (int i = t; i < n4; i += 256) {
        float4 v = r4[i];
        v.x -= L; v.y -= L; v.z -= L; v.w -= L;
        r4[i] = v;
    }
}

// ---------------------------------------------------------------------------
extern "C" void kernel_launch(void* const* d_in, const int* in_sizes, int n_in,
                              void* d_out, int out_size, void* d_ws, size_t ws_size,
                              hipStream_t stream)
{
    (void)in_sizes; (void)n_in; (void)out_size;
    const float* x      = (const float*)d_in[0];
    const int*   ei     = (const int*)d_in[1];
    const int*   et     = (const int*)d_in[2];
    const float* convW  = (const float*)d_in[3];
    const float* W0f    = (const float*)d_in[4];
    const float* gate   = (const float*)d_in[5];
    const float* globW  = (const float*)d_in[6];
    const float* globB  = (const float*)d_in[7];
    const float* senseW = (const float*)d_in[8];
    const float* senseB = (const float*)d_in[9];
    const float* mem0   = (const float*)d_in[10];
    float* out = (float*)d_out;

    // workspace layout (base ~8.4 MB; bf16 vocab weights above that)
    char* w = (char*)d_ws;
    unsigned short* Zb  = (unsigned short*)(w + 0);          // 512*1856*2 = 1900544
    unsigned short* Wcb = (unsigned short*)(w + 1900544);    // 384*1856*2 = 1425408
    unsigned short* x1b = (unsigned short*)(w + 3325952);    // 512*320*2  = 327680
    float* prop         = (float*)(w + 3653632);             // 3*512*304*4= 1867776
    float* scanA        = (float*)(w + 5521408);             // 512*304*4  = 622592
    float* pmax         = (float*)(w + 6144000);             // 548*512*4  = 1122304
    float* psum         = (float*)(w + 7266304);             // 548*512*4  = 1122304
    unsigned short* Wgb = (unsigned short*)(w + 8388608);    // 70144*320*2= 44892160
    const size_t WS_NEED_BIG = 8388608 + (size_t)WROWS * K2PAD * 2;  // ~53.28 MB
    bool bigws = ws_size >= WS_NEED_BIG;

    int zbase = bigws ? NB_W2 : 0;
    int nprep = zbase + NB_Z + NB_W;
    k_prep_all<<<nprep, 256, 0, stream>>>(x, ei, et, Zb, convW, W0f, Wcb,
                                          globW, senseW, Wgb, zbase);

    // stage-1: prop[z][512 x 304] partials = Zb . Wcb^T (split-K, 36 blocks)
    k_gemm_b<0><<<dim3(3, 4, NCHUNK), 256, 0, stream>>>(Zb, K1PAD, K1PAD, KCH,
        3, Wcb, K1PAD, nullptr, prop, 304, 304, 0,
        nullptr, 0, nullptr, nullptr, 0, 0, 0,
        nullptr, nullptr);

    k_scan_local<<<NSCH, 320, 0, stream>>>(prop, scanA, gate);
    k_finalize_x1<<<BDIM, 320, 0, stream>>>(scanA, mem0, gate, x1b);

    if (bigws) {
        const unsigned short* WgbS = Wgb + (size_t)GROWS * K2PAD;
        k_gemm_b<1><<<dim3(TGTOT, 4), 256, 0, stream>>>(x1b, K2PAD, K2PAD, 0,
            TG_GLOB, Wgb, K2PAD, globB, out, VGLOB, VGLOB, 0,
            WgbS, K2PAD, senseB, out + (size_t)BDIM * VGLOB, VSENSE, VSENSE, TG_GLOB,
            pmax, psum);
    } else {
        k_gemm_f32<<<dim3(TGTOT, 4), 256, 0, stream>>>(x1b, K2PAD, K2PAD,
            TG_GLOB, globW, DDIM, DDIM, VGLOB, globB, out, VGLOB, VGLOB, 0,
            senseW, DDIM, DDIM, VSENSE, senseB, out + (size_t)BDIM * VGLOB, VSENSE, VSENSE, TG_GLOB,
            pmax, psum);
    }
    k_lse_fix<<<dim3(BDIM, 2), 256, 0, stream>>>(pmax, psum, out);
}